// Round 21
// baseline (79.223 us; speedup 1.0000x reference)
//
#include <hip/hip_runtime.h>

#define NSTATE 128
#define NM1    127
#define UDIM   4

typedef float v4f  __attribute__((ext_vector_type(4)));
typedef _Float16 h2 __attribute__((ext_vector_type(2)));

// R21: R17 (best, 57.2us) with ONE change: 8 waves/block (512 thr) instead of
// 16 (1024 thr), grid still 256 (1 block/CU, 128KB LDS) -> 2048 concurrent
// write streams instead of 4096. fillBuffer achieves 7 TB/s with ~880
// streams; R13 showed MORE waves regress; FEWER never tested. Tighter
// instantaneous store front (2MB), fewer open-page conflicts per channel.
// Everything else identical to R17: fp16 W table in LDS, grid-dense pair
// mapping, lanes 0-31 = row 2p / 32-63 = row 2p+1, lane owns 4 cols,
// conflict-free ds_read_b128 x2, v_dot2_f32_f16, no-max softmax (validated
// R2-R20), 1KB nt store per wave.
// NT stores required (R15: plain +49%); dense front required (R17: +8us);
// no per-iter barrier (R18: +10%); lp stays in global (R19: LDS lp +5us);
// softmax stays fused (R20: split +13us).

__device__ __forceinline__ h2 as_h2(unsigned v) {
    union { unsigned u; h2 h; } c; c.u = v; return c.h;
}

__device__ __forceinline__ float dot2x2(unsigned wlo, unsigned whi, h2 u01, h2 u23) {
#if __has_builtin(__builtin_amdgcn_fdot2)
    return __builtin_amdgcn_fdot2(as_h2(wlo), u01,
           __builtin_amdgcn_fdot2(as_h2(whi), u23, 0.0f, false), false);
#else
    h2 a = as_h2(wlo), b = as_h2(whi);
    return (float)a[0] * (float)u01[0] + (float)a[1] * (float)u01[1]
         + (float)b[0] * (float)u23[0] + (float)b[1] * (float)u23[1];
#endif
}

// ---------------- pre-pass: pack fp16 table into ws ----------------
__global__ __launch_bounds__(128) void k_build_wh(
    const float* __restrict__ W, char* __restrict__ Wh)
{
    const int s = blockIdx.x;     // 0..127
    const int j = threadIdx.x;    // 0..127
    float4 w = make_float4(0.0f, 0.0f, 0.0f, 0.0f);
    if (j != s) {
        const int k = j - (j > s);
        w = *reinterpret_cast<const float4*>(W + ((size_t)s * NM1 + k) * UDIM);
    }
    h2 a; a[0] = (_Float16)w.x; a[1] = (_Float16)w.y;
    h2 b; b[0] = (_Float16)w.z; b[1] = (_Float16)w.w;
    const size_t off = (size_t)s * 1024 + (size_t)((j >> 1) & 1) * 512
                     + (size_t)(j >> 2) * 16 + (size_t)(j & 1) * 8;
    *reinterpret_cast<h2*>(Wh + off)     = a;
    *reinterpret_cast<h2*>(Wh + off + 4) = b;
}

// ---------------- hot kernel ----------------
__global__ __launch_bounds__(512) void k_seq(
    const int*   __restrict__ x_curr,
    const float* __restrict__ u_curr,
    const float* __restrict__ logP0,
    const uint4* __restrict__ Wh,
    float*       __restrict__ out,
    int T)
{
    __shared__ uint4 wt[8192];    // 128 KB

    const int tid = threadIdx.x;
    #pragma unroll
    for (int i = 0; i < 16; ++i)
        wt[tid + i * 512] = Wh[tid + i * 512];
    __syncthreads();

    const int lane = tid & 63;
    const int wv   = tid >> 6;      // 0..7
    const int h    = lane >> 5;     // 0 = row 2p, 1 = row 2p+1
    const int lh   = lane & 31;
    const int j0   = 4 * lh;

    const int npairs = (T + 1) >> 1;
    const int nw     = gridDim.x * 8;           // total waves (2048)
    const int pstart = blockIdx.x * 8 + wv;     // dense front: adjacent waves

    for (int p = pstart; p < npairs; p += nw) {
        const int r0 = 2 * p;
        const int r1 = (r0 + 1 < T) ? (r0 + 1) : r0;   // odd-T clamp (benign dup)

        int s0 = x_curr[r0], s1 = x_curr[r1];
        s0 = __builtin_amdgcn_readfirstlane(s0);
        s1 = __builtin_amdgcn_readfirstlane(s1);
        const int s = h ? s1 : s0;
        const int r = h ? r1 : r0;

        const float4 uv = *reinterpret_cast<const float4*>(u_curr + (size_t)r * UDIM);
        h2 u01; u01[0] = (_Float16)uv.x; u01[1] = (_Float16)uv.y;
        h2 u23; u23[0] = (_Float16)uv.z; u23[1] = (_Float16)uv.w;

        // cols 4lh,4lh+1 in w0; cols 4lh+2,4lh+3 in w1 (conflict-free b128)
        const uint4 w0 = wt[s * 64 + lh];
        const uint4 w1 = wt[s * 64 + 32 + lh];

        const float4 lp = *reinterpret_cast<const float4*>(logP0 + (size_t)s * NSTATE + j0);

        const float v0 = lp.x + dot2x2(w0.x, w0.y, u01, u23);
        const float v1 = lp.y + dot2x2(w0.z, w0.w, u01, u23);
        const float v2 = lp.z + dot2x2(w1.x, w1.y, u01, u23);
        const float v3 = lp.w + dot2x2(w1.z, w1.w, u01, u23);

        float e = (__expf(v0) + __expf(v1)) + (__expf(v2) + __expf(v3));
        #pragma unroll
        for (int o = 16; o >= 1; o >>= 1)
            e += __shfl_xor(e, o, 64);      // within 32-lane half
        const float l = __logf(e);

        v4f ov;
        ov[0] = v0 - l; ov[1] = v1 - l; ov[2] = v2 - l; ov[3] = v3 - l;
        __builtin_nontemporal_store(
            ov, reinterpret_cast<v4f*>(out + (size_t)r * NSTATE + j0));
    }
}

// ---------------- fallback (ws too small): R8-style direct kernel ----------------
__device__ __forceinline__ float dot4(const float4 a, const float4 b) {
    return fmaf(a.x, b.x, fmaf(a.y, b.y, fmaf(a.z, b.z, a.w * b.w)));
}

__global__ __launch_bounds__(256) void k_fallback(
    const int* __restrict__ x_curr, const float* __restrict__ u_curr,
    const float* __restrict__ logP0, const float* __restrict__ W,
    float* __restrict__ out, int T)
{
    const int lane    = threadIdx.x & 63;
    const int wave_id = (blockIdx.x * blockDim.x + threadIdx.x) >> 6;
    const int nwaves  = (gridDim.x * blockDim.x) >> 6;
    const int j0 = 2 * lane, j1 = j0 + 1;
    for (int t = wave_id; t < T; t += nwaves) {
        int s = x_curr[t];
        s = __builtin_amdgcn_readfirstlane(s);
        const float4 uv = *reinterpret_cast<const float4*>(u_curr + (size_t)t * UDIM);
        float st0 = 0.0f, st1 = 0.0f;
        if (j0 != s) {
            const int k = j0 - (j0 > s);
            const float4 w = *reinterpret_cast<const float4*>(W + ((size_t)s * NM1 + k) * UDIM);
            st0 = dot4(uv, w);
        }
        if (j1 != s) {
            const int k = j1 - (j1 > s);
            const float4 w = *reinterpret_cast<const float4*>(W + ((size_t)s * NM1 + k) * UDIM);
            st1 = dot4(uv, w);
        }
        const float2 lp = *reinterpret_cast<const float2*>(logP0 + (size_t)s * NSTATE + j0);
        const float v0 = lp.x + st0, v1 = lp.y + st1;
        float e = __expf(v0) + __expf(v1);
        #pragma unroll
        for (int o = 32; o >= 1; o >>= 1)
            e += __shfl_xor(e, o, 64);
        const float l = __logf(e);
        float2 o2; o2.x = v0 - l; o2.y = v1 - l;
        *reinterpret_cast<float2*>(out + (size_t)t * NSTATE + j0) = o2;
    }
}

extern "C" void kernel_launch(void* const* d_in, const int* in_sizes, int n_in,
                              void* d_out, int out_size, void* d_ws, size_t ws_size,
                              hipStream_t stream) {
    const int*   x_curr = (const int*)  d_in[0];
    const float* u_curr = (const float*)d_in[1];
    const float* logP0  = (const float*)d_in[2];
    const float* W      = (const float*)d_in[3];
    float*       out    = (float*)d_out;

    const int T = in_sizes[0];
    const size_t need = 131072;   // 128 KB fp16 table

    if (ws_size < need || T < 2) {
        hipLaunchKernelGGL(k_fallback, dim3(2048), dim3(256), 0, stream,
                           x_curr, u_curr, logP0, W, out, T);
        return;
    }

    hipLaunchKernelGGL(k_build_wh, dim3(NSTATE), dim3(NSTATE), 0, stream,
                       W, (char*)d_ws);

    // 256 blocks x 512 thr (1 block/CU, 128KB LDS, 8 waves/CU);
    // grid-dense pair mapping, 2048 write streams.
    hipLaunchKernelGGL(k_seq, dim3(256), dim3(512), 0, stream,
                       x_curr, u_curr, logP0, (const uint4*)d_ws, out, T);
}

// Round 22
// 57.845 us; speedup vs baseline: 1.3696x; 1.3696x over previous
//
#include <hip/hip_runtime.h>

#define NSTATE 128
#define NM1    127
#define UDIM   4

typedef float v4f  __attribute__((ext_vector_type(4)));
typedef _Float16 h2 __attribute__((ext_vector_type(2)));

// R22 = FINAL: exact revert to R17 (best, 57.2us).
// Structure: fp16 de-interleaved W table (128KB) in LDS; 256 blocks x 1024
// thr (1 block/CU, 16 waves); grid-dense pair mapping p = blk*16 + wv +
// it*4096 (the grid's nt stores form one dense moving front); lanes 0-31 =
// row 2p, 32-63 = row 2p+1, lane owns 4 cols; conflict-free ds_read_b128 x2;
// v_dot2_f32_f16 dots; no-max softmax (validated R2-R21, absmax 0.0625 vs
// thr 0.186); 1KB nt store per wave.
// Locked-in findings: nt stores required (R15 plain +49%); dense front
// required (R17 +8us vs spans); 16 waves/CU optimal (R21 8w +38%, R13 more
// waves +3%); no per-iter barrier (R18 +10%); lp in global (R19 LDS lp +9%);
// softmax fused (R20 split +23%); ILP/pipelining null (R4/R5/R6/R16).
// Hot kernel ~54us ~= 4.7 TB/s effective write vs 7 TB/s pure-fill ref;
// residual = MC read/write turnaround (R20: compute-free loop no faster).

__device__ __forceinline__ h2 as_h2(unsigned v) {
    union { unsigned u; h2 h; } c; c.u = v; return c.h;
}

__device__ __forceinline__ float dot2x2(unsigned wlo, unsigned whi, h2 u01, h2 u23) {
#if __has_builtin(__builtin_amdgcn_fdot2)
    return __builtin_amdgcn_fdot2(as_h2(wlo), u01,
           __builtin_amdgcn_fdot2(as_h2(whi), u23, 0.0f, false), false);
#else
    h2 a = as_h2(wlo), b = as_h2(whi);
    return (float)a[0] * (float)u01[0] + (float)a[1] * (float)u01[1]
         + (float)b[0] * (float)u23[0] + (float)b[1] * (float)u23[1];
#endif
}

// ---------------- pre-pass: pack fp16 table into ws ----------------
__global__ __launch_bounds__(128) void k_build_wh(
    const float* __restrict__ W, char* __restrict__ Wh)
{
    const int s = blockIdx.x;     // 0..127
    const int j = threadIdx.x;    // 0..127
    float4 w = make_float4(0.0f, 0.0f, 0.0f, 0.0f);
    if (j != s) {
        const int k = j - (j > s);
        w = *reinterpret_cast<const float4*>(W + ((size_t)s * NM1 + k) * UDIM);
    }
    h2 a; a[0] = (_Float16)w.x; a[1] = (_Float16)w.y;
    h2 b; b[0] = (_Float16)w.z; b[1] = (_Float16)w.w;
    const size_t off = (size_t)s * 1024 + (size_t)((j >> 1) & 1) * 512
                     + (size_t)(j >> 2) * 16 + (size_t)(j & 1) * 8;
    *reinterpret_cast<h2*>(Wh + off)     = a;
    *reinterpret_cast<h2*>(Wh + off + 4) = b;
}

// ---------------- hot kernel ----------------
__global__ __launch_bounds__(1024) void k_seq(
    const int*   __restrict__ x_curr,
    const float* __restrict__ u_curr,
    const float* __restrict__ logP0,
    const uint4* __restrict__ Wh,
    float*       __restrict__ out,
    int T)
{
    __shared__ uint4 wt[8192];    // 128 KB

    const int tid = threadIdx.x;
    #pragma unroll
    for (int i = 0; i < 8; ++i)
        wt[tid + i * 1024] = Wh[tid + i * 1024];
    __syncthreads();

    const int lane = tid & 63;
    const int wv   = tid >> 6;      // 0..15
    const int h    = lane >> 5;     // 0 = row 2p, 1 = row 2p+1
    const int lh   = lane & 31;
    const int j0   = 4 * lh;

    const int npairs = (T + 1) >> 1;
    const int nw     = gridDim.x * 16;          // total waves (4096)
    const int pstart = blockIdx.x * 16 + wv;    // dense front: adjacent waves

    for (int p = pstart; p < npairs; p += nw) {
        const int r0 = 2 * p;
        const int r1 = (r0 + 1 < T) ? (r0 + 1) : r0;   // odd-T clamp (benign dup)

        int s0 = x_curr[r0], s1 = x_curr[r1];
        s0 = __builtin_amdgcn_readfirstlane(s0);
        s1 = __builtin_amdgcn_readfirstlane(s1);
        const int s = h ? s1 : s0;
        const int r = h ? r1 : r0;

        const float4 uv = *reinterpret_cast<const float4*>(u_curr + (size_t)r * UDIM);
        h2 u01; u01[0] = (_Float16)uv.x; u01[1] = (_Float16)uv.y;
        h2 u23; u23[0] = (_Float16)uv.z; u23[1] = (_Float16)uv.w;

        // cols 4lh,4lh+1 in w0; cols 4lh+2,4lh+3 in w1 (conflict-free b128)
        const uint4 w0 = wt[s * 64 + lh];
        const uint4 w1 = wt[s * 64 + 32 + lh];

        const float4 lp = *reinterpret_cast<const float4*>(logP0 + (size_t)s * NSTATE + j0);

        const float v0 = lp.x + dot2x2(w0.x, w0.y, u01, u23);
        const float v1 = lp.y + dot2x2(w0.z, w0.w, u01, u23);
        const float v2 = lp.z + dot2x2(w1.x, w1.y, u01, u23);
        const float v3 = lp.w + dot2x2(w1.z, w1.w, u01, u23);

        float e = (__expf(v0) + __expf(v1)) + (__expf(v2) + __expf(v3));
        #pragma unroll
        for (int o = 16; o >= 1; o >>= 1)
            e += __shfl_xor(e, o, 64);      // within 32-lane half
        const float l = __logf(e);

        v4f ov;
        ov[0] = v0 - l; ov[1] = v1 - l; ov[2] = v2 - l; ov[3] = v3 - l;
        __builtin_nontemporal_store(
            ov, reinterpret_cast<v4f*>(out + (size_t)r * NSTATE + j0));
    }
}

// ---------------- fallback (ws too small): direct kernel ----------------
__device__ __forceinline__ float dot4(const float4 a, const float4 b) {
    return fmaf(a.x, b.x, fmaf(a.y, b.y, fmaf(a.z, b.z, a.w * b.w)));
}

__global__ __launch_bounds__(256) void k_fallback(
    const int* __restrict__ x_curr, const float* __restrict__ u_curr,
    const float* __restrict__ logP0, const float* __restrict__ W,
    float* __restrict__ out, int T)
{
    const int lane    = threadIdx.x & 63;
    const int wave_id = (blockIdx.x * blockDim.x + threadIdx.x) >> 6;
    const int nwaves  = (gridDim.x * blockDim.x) >> 6;
    const int j0 = 2 * lane, j1 = j0 + 1;
    for (int t = wave_id; t < T; t += nwaves) {
        int s = x_curr[t];
        s = __builtin_amdgcn_readfirstlane(s);
        const float4 uv = *reinterpret_cast<const float4*>(u_curr + (size_t)t * UDIM);
        float st0 = 0.0f, st1 = 0.0f;
        if (j0 != s) {
            const int k = j0 - (j0 > s);
            const float4 w = *reinterpret_cast<const float4*>(W + ((size_t)s * NM1 + k) * UDIM);
            st0 = dot4(uv, w);
        }
        if (j1 != s) {
            const int k = j1 - (j1 > s);
            const float4 w = *reinterpret_cast<const float4*>(W + ((size_t)s * NM1 + k) * UDIM);
            st1 = dot4(uv, w);
        }
        const float2 lp = *reinterpret_cast<const float2*>(logP0 + (size_t)s * NSTATE + j0);
        const float v0 = lp.x + st0, v1 = lp.y + st1;
        float e = __expf(v0) + __expf(v1);
        #pragma unroll
        for (int o = 32; o >= 1; o >>= 1)
            e += __shfl_xor(e, o, 64);
        const float l = __logf(e);
        float2 o2; o2.x = v0 - l; o2.y = v1 - l;
        *reinterpret_cast<float2*>(out + (size_t)t * NSTATE + j0) = o2;
    }
}

extern "C" void kernel_launch(void* const* d_in, const int* in_sizes, int n_in,
                              void* d_out, int out_size, void* d_ws, size_t ws_size,
                              hipStream_t stream) {
    const int*   x_curr = (const int*)  d_in[0];
    const float* u_curr = (const float*)d_in[1];
    const float* logP0  = (const float*)d_in[2];
    const float* W      = (const float*)d_in[3];
    float*       out    = (float*)d_out;

    const int T = in_sizes[0];
    const size_t need = 131072;   // 128 KB fp16 table

    if (ws_size < need || T < 2) {
        hipLaunchKernelGGL(k_fallback, dim3(2048), dim3(256), 0, stream,
                           x_curr, u_curr, logP0, W, out, T);
        return;
    }

    hipLaunchKernelGGL(k_build_wh, dim3(NSTATE), dim3(NSTATE), 0, stream,
                       W, (char*)d_ws);

    // 256 blocks x 1024 thr (1 block/CU, 128KB LDS); grid-dense pair mapping.
    hipLaunchKernelGGL(k_seq, dim3(256), dim3(1024), 0, stream,
                       x_curr, u_curr, logP0, (const uint4*)d_ws, out, T);
}